// Round 7
// baseline (812.771 us; speedup 1.0000x reference)
//
#include <hip/hip_runtime.h>

// 4-layer LSTM (B=1024,T=512,H=64,G=256) + FC head.
// ROUND 14 (r7 of session): counted-waitcnt barrier (T3/T4 discipline) on the nowrap winner.
//   r6 result: nowrap (servo-free ring) 794 -> 748us. Superstep now ~3495cyc, per-SIMD issue
//   ~1300-1500 (VALUBusy 42.8%/active-CU). Remaining ~2000cyc base stall theory:
//   __syncthreads() drains vmcnt(0) every superstep, exposing the ~600-900cyc HBM latency of
//   the post-barrier ring stores/loads + x-prefetch issued only ~600-800cyc earlier; barrier
//   propagates the worst wave to all 8. None of that traffic needs to drain at the barrier
//   (FIFO depth-3 / flag lag-2 slack). Fix (guide m201-verified pattern):
//     loop barrier = s_waitcnt lgkmcnt(0) [+ vmcnt(4) on producer-grp1 only] ; s_barrier.
//   Flag math stays sound: vmcnt(4) at barrier s retires all but slot s-1's 4 stores ->
//   flag s-1 (published post-barrier s) still implies slot <= s-2 durable. Loads are
//   register-targeted: compiler waits at USE (1-3 supersteps of slack preserved).
// Kernel N2 (lstm_nowrap2): primary. Kernel A (lstm_split): servo champion fallback
// (ws < 64MB). Kernel B (lstm_fused): no-ws fallback.

#define TLEN 512
#define NCH  64
#define AG   __HIP_MEMORY_SCOPE_AGENT
#define SPIN_CAP 2000000
#define LOG2E 1.44269504f
#define TWOLOG2E 2.88539008f

typedef __bf16 bf16x8 __attribute__((ext_vector_type(8)));
typedef float  f32x4  __attribute__((ext_vector_type(4)));

struct Params {
  const float* x;
  const float* wih[4]; const float* whh[4];
  const float* bih[4]; const float* bhh[4];
  const float* fc1w; const float* fc1b;
  const float* fc2w; const float* fc2b;
  float* out; char* ws;
  int CAP; int CM;
};

__device__ __forceinline__ bf16x8 bfzero() {
  union { unsigned long long u[2]; bf16x8 v; } z; z.u[0] = 0ull; z.u[1] = 0ull; return z.v;
}
__device__ __forceinline__ float fast_sigmoid(float x) {
  return __builtin_amdgcn_rcpf(1.f + __expf(-x));
}
__device__ __forceinline__ float fast_tanh(float x) {
  float e = __expf(2.f * x);
  return 1.f - 2.f * __builtin_amdgcn_rcpf(e + 1.f);
}
__device__ __forceinline__ void load_frag_pair(const unsigned short* sb, int l15, int quad,
                                               bf16x8& f0, bf16x8& f1) {
  const unsigned long long* a = (const unsigned long long*)(sb + l15 * 64 + quad * 8);
  const unsigned long long* b = (const unsigned long long*)(sb + l15 * 64 + 32 + quad * 8);
  union { bf16x8 v; unsigned long long u[2]; } c0, c1;
  c0.u[0] = __hip_atomic_load(&a[0], __ATOMIC_RELAXED, AG);
  c0.u[1] = __hip_atomic_load(&a[1], __ATOMIC_RELAXED, AG);
  c1.u[0] = __hip_atomic_load(&b[0], __ATOMIC_RELAXED, AG);
  c1.u[1] = __hip_atomic_load(&b[1], __ATOMIC_RELAXED, AG);
  f0 = c0.v; f1 = c1.v;
}

// ====== Kernel N2: nowrap structure + counted-waitcnt raw barrier (no vmcnt(0) drain) =====
__global__ __launch_bounds__(512, 2) void lstm_nowrap2(Params p)
{
  const int bid   = blockIdx.x;
  const int role  = bid >> 6;
  const int chunk = bid & 63;
  const int b0    = chunk * 16;
  const int tid   = threadIdx.x;
  const int wave  = tid >> 6;
  const int grp   = wave >> 2;
  const int w     = wave & 3;
  const int lane  = tid & 63;
  const int quad  = lane >> 4;
  const int l15   = lane & 15;
  const int L     = role * 2 + grp;

  __shared__ __bf16 tiles[2][2][1024];
  __shared__ float  s_fc1w[2048];
  __shared__ float  s_z[512];
  __shared__ float  s_fc1b[32];
  __shared__ float  s_fc2w[96];
  __shared__ float  s_fc2b[3];

  int* flagp = (int*)p.ws + chunk * 16;
  unsigned short* ringc = (unsigned short*)(p.ws + 32 * 1024) + (size_t)chunk * 512 * 1024;

  // ---- weight fragments wf[gate][frag]: 0-1 = Wih(K0..63), 2-3 = Whh(K0..63) ----
  // exp2 folding (r8-verified): i,f,o scaled -log2e; g scaled +2log2e.
  bf16x8 wf[4][4];
  float  bias[4];
  {
    const float gsc[4] = { -LOG2E, -LOG2E, TWOLOG2E, -LOG2E };
    const float* wih = p.wih[L];
    const float* whh = p.whh[L];
    const float* bih = p.bih[L];
    const float* bhh = p.bhh[L];
#pragma unroll
    for (int g = 0; g < 4; g++) {
      const float sc = gsc[g];
      int n = g * 64 + w * 16 + l15;
      bias[g] = (bih[n] + bhh[n]) * sc;
      if (L == 0) {                    // w_ih_0 is (256,4): K-pad, frag1 unused
        bf16x8 f = bfzero();
        if (quad == 0) {
#pragma unroll
          for (int j = 0; j < 4; j++) f[j] = (__bf16)(wih[n * 4 + j] * sc);
        }
        wf[g][0] = f; wf[g][1] = bfzero();
      } else {
#pragma unroll
        for (int q = 0; q < 2; q++) {
          const float* s = wih + n * 64 + q * 32 + quad * 8;
          bf16x8 f;
#pragma unroll
          for (int j = 0; j < 8; j++) f[j] = (__bf16)(s[j] * sc);
          wf[g][q] = f;
        }
      }
#pragma unroll
      for (int q = 0; q < 2; q++) {
        const float* s = whh + n * 64 + q * 32 + quad * 8;
        bf16x8 f;
#pragma unroll
        for (int j = 0; j < 8; j++) f[j] = (__bf16)(s[j] * sc);
        wf[g][2 + q] = f;
      }
    }
  }

  { int* ti = (int*)tiles; for (int i = tid; i < 2048; i += 512) ti[i] = 0; }
  float cst[4] = {0.f, 0.f, 0.f, 0.f};

  int W = -1000000000, f_pend = -1000000000;
  bf16x8 xA0 = bfzero(), xA1 = bfzero();
  bf16x8 xB0 = bfzero(), xB1 = bfzero();
  bf16x8 xC0 = bfzero(), xC1 = bfzero();
  float4 xraw = {0.f, 0.f, 0.f, 0.f};

  if (role == 0) {
    if (grp == 0 && quad == 0) {
      const float* xb = p.x + (size_t)(b0 + l15) * TLEN * 4;
      const float4 x0 = *(const float4*)(xb);
      const float4 x1 = *(const float4*)(xb + 4);
      xraw = *(const float4*)(xb + 8);
      bf16x8 f = bfzero();
      f[0] = (__bf16)x0.x; f[1] = (__bf16)x0.y; f[2] = (__bf16)x0.z; f[3] = (__bf16)x0.w;
      xA0 = f;
      bf16x8 g = bfzero();
      g[0] = (__bf16)x1.x; g[1] = (__bf16)x1.y; g[2] = (__bf16)x1.z; g[3] = (__bf16)x1.w;
      xB0 = g;
    }
  } else if (grp == 0) {
    // start gate: tight sleep-free spin (one-time)
    int v = -1000000000, it = 0;
    do {
      if (lane == 0) v = __hip_atomic_load(flagp, __ATOMIC_ACQUIRE, AG);
      v = __shfl(v, 0);
      if (v >= 10) break;
    } while (++it < SPIN_CAP);
    W = v;
    load_frag_pair(ringc,        l15, quad, xA0, xA1);   // slot 0
    load_frag_pair(ringc + 1024, l15, quad, xB0, xB1);   // slot 1
    load_frag_pair(ringc + 2048, l15, quad, xC0, xC1);   // slot 2
  }
  __syncthreads();   // cold-path barrier: full drain ok

  const int SMAX = (role == 0) ? (TLEN + 2) : (TLEN + 1);
  for (int s = 0; s < SMAX; s++) {
    const int t  = s - grp;
    const int pr = s & 1, pw = pr ^ 1;
    unsigned hb[4];

    if ((unsigned)t < (unsigned)TLEN) {
      bf16x8 if0, if1;
      if (grp == 0) { if0 = xA0; if1 = xA1; }
      else {
        const __bf16* src = tiles[pr][0];
        int sg0 = quad ^ (l15 & 7);
        int sg1 = (4 + quad) ^ (l15 & 7);
        if0 = *(const bf16x8*)&src[l15 * 64 + sg0 * 8];
        if1 = *(const bf16x8*)&src[l15 * 64 + sg1 * 8];
      }
      bf16x8 hf0, hf1;
      {
        const __bf16* src = tiles[pr][grp];
        int sg0 = quad ^ (l15 & 7);
        int sg1 = (4 + quad) ^ (l15 & 7);
        hf0 = *(const bf16x8*)&src[l15 * 64 + sg0 * 8];
        hf1 = *(const bf16x8*)&src[l15 * 64 + sg1 * 8];
      }

      f32x4 acc[4];
#pragma unroll
      for (int g = 0; g < 4; g++) { f32x4 a = {bias[g], bias[g], bias[g], bias[g]}; acc[g] = a; }
      if (L == 0) {
#pragma unroll
        for (int g = 0; g < 4; g++)
          acc[g] = __builtin_amdgcn_mfma_f32_16x16x32_bf16(if0, wf[g][0], acc[g], 0, 0, 0);
      } else {
#pragma unroll
        for (int g = 0; g < 4; g++) {
          acc[g] = __builtin_amdgcn_mfma_f32_16x16x32_bf16(if0, wf[g][0], acc[g], 0, 0, 0);
          acc[g] = __builtin_amdgcn_mfma_f32_16x16x32_bf16(if1, wf[g][1], acc[g], 0, 0, 0);
        }
      }
#pragma unroll
      for (int g = 0; g < 4; g++) {
        acc[g] = __builtin_amdgcn_mfma_f32_16x16x32_bf16(hf0, wf[g][2], acc[g], 0, 0, 0);
        acc[g] = __builtin_amdgcn_mfma_f32_16x16x32_bf16(hf1, wf[g][3], acc[g], 0, 0, 0);
      }

      // cell (exp2-folded): acc_i/f/o = -log2e*pre, acc_g = 2log2e*pre
      const int col = w * 16 + l15;
      __bf16* dst = tiles[pw][grp];
#pragma unroll
      for (int r = 0; r < 4; r++) {
        float ig = __builtin_amdgcn_rcpf(1.f + __builtin_amdgcn_exp2f(acc[0][r]));
        float fg = __builtin_amdgcn_rcpf(1.f + __builtin_amdgcn_exp2f(acc[1][r]));
        float gg = 1.f - 2.f * __builtin_amdgcn_rcpf(1.f + __builtin_amdgcn_exp2f(acc[2][r]));
        float og = __builtin_amdgcn_rcpf(1.f + __builtin_amdgcn_exp2f(acc[3][r]));
        float c  = fg * cst[r] + ig * gg;
        cst[r] = c;
        float th = 1.f - 2.f * __builtin_amdgcn_rcpf(1.f + __builtin_amdgcn_exp2f(TWOLOG2E * c));
        float h  = og * th;
        __bf16 hbf = (__bf16)h;
        union { __bf16 b; unsigned short s; } cv; cv.b = hbf;
        hb[r] = cv.s;
        int m  = quad * 4 + r;
        int sg = (col >> 3) ^ (m & 7);
        dst[m * 64 + sg * 8 + (col & 7)] = hbf;
      }
    }

    // ---- counted-waitcnt barrier (replaces __syncthreads' vmcnt(0) drain) ----
    // LDS handoff ordering: my tile writes committed before the barrier.
    // Producer grp1 additionally retires all ring stores except the newest 4 (slot s-1),
    // which keeps the flag protocol sound (flag s-1 gates slots <= s-2, drained here).
    if (role == 0 && grp == 1)
      asm volatile("s_waitcnt vmcnt(4)" ::: "memory");
    asm volatile("s_waitcnt lgkmcnt(0)" ::: "memory");
    __builtin_amdgcn_s_barrier();
    asm volatile("" ::: "memory");   // keep post-barrier memory ops after the barrier

    // -------- post-barrier cross-block work (fire & forget; consumed >=1 step later) -----
    if (role == 0) {
      if (grp == 0) {
        xA0 = xB0;
        if (quad == 0) {
          bf16x8 f = bfzero();
          f[0] = (__bf16)xraw.x; f[1] = (__bf16)xraw.y;
          f[2] = (__bf16)xraw.z; f[3] = (__bf16)xraw.w;
          xB0 = f;
          if (t + 3 < TLEN)
            xraw = *(const float4*)(p.x + ((size_t)(b0 + l15) * TLEN + (t + 3)) * 4);
        }
      }
      if (grp == 1 && (unsigned)t < (unsigned)TLEN) {
        // no ack servo, no throttle: slot t is written exactly once, never overwritten
        const int col = w * 16 + l15;
        unsigned* rdst = (unsigned*)(ringc + (size_t)t * 1024);
#pragma unroll
        for (int r = 0; r < 4; r++) {
          unsigned v = hb[r];
          unsigned o = (unsigned)__shfl_xor((int)v, 1);
          if ((lane & 1) == 0) {
            int m = quad * 4 + r;
            __hip_atomic_store(&rdst[(m * 64 + col) >> 1], v | (o << 16), __ATOMIC_RELAXED, AG);
          }
        }
      }
      if (tid == 0 && s >= 2)
        __hip_atomic_store(flagp, s - 1, __ATOMIC_RELAXED, AG);
    } else {
      if (grp == 0) {
        int fm = __shfl(f_pend, 0);
        if (fm > W) W = fm;
        if (lane == 0) f_pend = __hip_atomic_load(flagp, __ATOMIC_RELAXED, AG);
        xA0 = xB0; xA1 = xB1; xB0 = xC0; xB1 = xC1;
        if (t + 3 < TLEN) {
          if (W < t + 4) {
            // rare jitter catch-up: tight sleep-free spin
            int v = W, it = 0;
            do {
              if (lane == 0) v = __hip_atomic_load(flagp, __ATOMIC_ACQUIRE, AG);
              v = __shfl(v, 0);
              if (v >= t + 4) break;
            } while (++it < SPIN_CAP);
            W = v;
          }
          load_frag_pair(ringc + (size_t)(t + 3) * 1024, l15, quad, xC0, xC1);
        }
      }
      // no ack publish
    }
  }

  // ---- FC head + softmax (consumer; L3 final h at superstep 512 -> parity 1) ----
  if (role == 1) {
    for (int i = tid; i < 2048; i += 512) s_fc1w[i] = p.fc1w[i];
    if (tid < 32) s_fc1b[tid] = p.fc1b[tid];
    if (tid < 96) s_fc2w[tid] = p.fc2w[tid];
    if (tid < 3)  s_fc2b[tid] = p.fc2b[tid];
    __syncthreads();
    {
      int m = tid >> 5, u = tid & 31;
      float sacc = s_fc1b[u];
      const float* wrow = &s_fc1w[u * 64];
      const __bf16* hfin = tiles[1][1];
#pragma unroll
      for (int k = 0; k < 64; k++) {
        int sg = (k >> 3) ^ (m & 7);
        sacc += (float)hfin[m * 64 + sg * 8 + (k & 7)] * wrow[k];
      }
      s_z[m * 32 + u] = fmaxf(sacc, 0.f);
    }
    __syncthreads();
    if (tid < 16) {
      int m = tid;
      float lg[3];
#pragma unroll
      for (int v = 0; v < 3; v++) {
        float sv = s_fc2b[v];
#pragma unroll
        for (int u = 0; u < 32; u++) sv += s_z[m * 32 + u] * s_fc2w[v * 32 + u];
        lg[v] = sv;
      }
      float mx = fmaxf(lg[0], fmaxf(lg[1], lg[2]));
      float e0 = __expf(lg[0] - mx), e1 = __expf(lg[1] - mx), e2 = __expf(lg[2] - mx);
      float inv = 1.f / (e0 + e1 + e2);
      float* o = p.out + (size_t)(b0 + m) * 3;
      o[0] = e0 * inv; o[1] = e1 * inv; o[2] = e2 * inv;
    }
  }
}

// ================= Kernel A: servo champion (794us) — fallback ws<64MB ==================
__global__ __launch_bounds__(512, 2) void lstm_split(Params p)
{
  const int bid   = blockIdx.x;
  const int role  = bid >> 6;
  const int chunk = bid & 63;
  const int b0    = chunk * 16;
  const int tid   = threadIdx.x;
  const int wave  = tid >> 6;
  const int grp   = wave >> 2;
  const int w     = wave & 3;
  const int lane  = tid & 63;
  const int quad  = lane >> 4;
  const int l15   = lane & 15;
  const int L     = role * 2 + grp;

  __shared__ __bf16 tiles[2][2][1024];
  __shared__ float  s_fc1w[2048];
  __shared__ float  s_z[512];
  __shared__ float  s_fc1b[32];
  __shared__ float  s_fc2w[96];
  __shared__ float  s_fc2b[3];

  int* flagp = (int*)p.ws + chunk * 16;
  int* ackp  = (int*)(p.ws + 16 * 1024) + chunk * 16;
  unsigned short* ringc = (unsigned short*)(p.ws + 32 * 1024) + (size_t)chunk * p.CAP * 1024;
  const int CAP = p.CAP, CM = p.CM;

  bf16x8 wf[4][4];
  float  bias[4];
  {
    const float gsc[4] = { -LOG2E, -LOG2E, TWOLOG2E, -LOG2E };
    const float* wih = p.wih[L];
    const float* whh = p.whh[L];
    const float* bih = p.bih[L];
    const float* bhh = p.bhh[L];
#pragma unroll
    for (int g = 0; g < 4; g++) {
      const float sc = gsc[g];
      int n = g * 64 + w * 16 + l15;
      bias[g] = (bih[n] + bhh[n]) * sc;
      if (L == 0) {
        bf16x8 f = bfzero();
        if (quad == 0) {
#pragma unroll
          for (int j = 0; j < 4; j++) f[j] = (__bf16)(wih[n * 4 + j] * sc);
        }
        wf[g][0] = f; wf[g][1] = bfzero();
      } else {
#pragma unroll
        for (int q = 0; q < 2; q++) {
          const float* s = wih + n * 64 + q * 32 + quad * 8;
          bf16x8 f;
#pragma unroll
          for (int j = 0; j < 8; j++) f[j] = (__bf16)(s[j] * sc);
          wf[g][q] = f;
        }
      }
#pragma unroll
      for (int q = 0; q < 2; q++) {
        const float* s = whh + n * 64 + q * 32 + quad * 8;
        bf16x8 f;
#pragma unroll
        for (int j = 0; j < 8; j++) f[j] = (__bf16)(s[j] * sc);
        wf[g][2 + q] = f;
      }
    }
  }

  { int* ti = (int*)tiles; for (int i = tid; i < 2048; i += 512) ti[i] = 0; }
  float cst[4] = {0.f, 0.f, 0.f, 0.f};

  int W = -1000000000, f_pend = -1000000000;
  int ackW = -1000000000, a_pend = -1000000000;
  bf16x8 xA0 = bfzero(), xA1 = bfzero();
  bf16x8 xB0 = bfzero(), xB1 = bfzero();
  bf16x8 xC0 = bfzero(), xC1 = bfzero();
  float4 xraw = {0.f, 0.f, 0.f, 0.f};

  if (role == 0) {
    if (grp == 0 && quad == 0) {
      const float* xb = p.x + (size_t)(b0 + l15) * TLEN * 4;
      const float4 x0 = *(const float4*)(xb);
      const float4 x1 = *(const float4*)(xb + 4);
      xraw = *(const float4*)(xb + 8);
      bf16x8 f = bfzero();
      f[0] = (__bf16)x0.x; f[1] = (__bf16)x0.y; f[2] = (__bf16)x0.z; f[3] = (__bf16)x0.w;
      xA0 = f;
      bf16x8 g = bfzero();
      g[0] = (__bf16)x1.x; g[1] = (__bf16)x1.y; g[2] = (__bf16)x1.z; g[3] = (__bf16)x1.w;
      xB0 = g;
    }
  } else if (grp == 0) {
    int v = -1000000000, it = 0;
    do {
      if (lane == 0) v = __hip_atomic_load(flagp, __ATOMIC_ACQUIRE, AG);
      v = __shfl(v, 0);
      if (v >= 10) break;
      __builtin_amdgcn_s_sleep(1);
    } while (++it < SPIN_CAP);
    W = v;
    load_frag_pair(ringc,        l15, quad, xA0, xA1);
    load_frag_pair(ringc + 1024, l15, quad, xB0, xB1);
    load_frag_pair(ringc + 2048, l15, quad, xC0, xC1);
  }
  __syncthreads();

  const int SMAX = (role == 0) ? (TLEN + 2) : (TLEN + 1);
  for (int s = 0; s < SMAX; s++) {
    const int t  = s - grp;
    const int pr = s & 1, pw = pr ^ 1;
    unsigned hb[4];

    if ((unsigned)t < (unsigned)TLEN) {
      bf16x8 if0, if1;
      if (grp == 0) { if0 = xA0; if1 = xA1; }
      else {
        const __bf16* src = tiles[pr][0];
        int sg0 = quad ^ (l15 & 7);
        int sg1 = (4 + quad) ^ (l15 & 7);
        if0 = *(const bf16x8*)&src[l15 * 64 + sg0 * 8];
        if1 = *(const bf16x8*)&src[l15 * 64 + sg1 * 8];
      }
      bf16x8 hf0, hf1;
      {
        const __bf16* src = tiles[pr][grp];
        int sg0 = quad ^ (l15 & 7);
        int sg1 = (4 + quad) ^ (l15 & 7);
        hf0 = *(const bf16x8*)&src[l15 * 64 + sg0 * 8];
        hf1 = *(const bf16x8*)&src[l15 * 64 + sg1 * 8];
      }

      f32x4 acc[4];
#pragma unroll
      for (int g = 0; g < 4; g++) { f32x4 a = {bias[g], bias[g], bias[g], bias[g]}; acc[g] = a; }
      if (L == 0) {
#pragma unroll
        for (int g = 0; g < 4; g++)
          acc[g] = __builtin_amdgcn_mfma_f32_16x16x32_bf16(if0, wf[g][0], acc[g], 0, 0, 0);
      } else {
#pragma unroll
        for (int g = 0; g < 4; g++) {
          acc[g] = __builtin_amdgcn_mfma_f32_16x16x32_bf16(if0, wf[g][0], acc[g], 0, 0, 0);
          acc[g] = __builtin_amdgcn_mfma_f32_16x16x32_bf16(if1, wf[g][1], acc[g], 0, 0, 0);
        }
      }
#pragma unroll
      for (int g = 0; g < 4; g++) {
        acc[g] = __builtin_amdgcn_mfma_f32_16x16x32_bf16(hf0, wf[g][2], acc[g], 0, 0, 0);
        acc[g] = __builtin_amdgcn_mfma_f32_16x16x32_bf16(hf1, wf[g][3], acc[g], 0, 0, 0);
      }

      const int col = w * 16 + l15;
      __bf16* dst = tiles[pw][grp];
#pragma unroll
      for (int r = 0; r < 4; r++) {
        float ig = __builtin_amdgcn_rcpf(1.f + __builtin_amdgcn_exp2f(acc[0][r]));
        float fg = __builtin_amdgcn_rcpf(1.f + __builtin_amdgcn_exp2f(acc[1][r]));
        float gg = 1.f - 2.f * __builtin_amdgcn_rcpf(1.f + __builtin_amdgcn_exp2f(acc[2][r]));
        float og = __builtin_amdgcn_rcpf(1.f + __builtin_amdgcn_exp2f(acc[3][r]));
        float c  = fg * cst[r] + ig * gg;
        cst[r] = c;
        float th = 1.f - 2.f * __builtin_amdgcn_rcpf(1.f + __builtin_amdgcn_exp2f(TWOLOG2E * c));
        float h  = og * th;
        __bf16 hbf = (__bf16)h;
        union { __bf16 b; unsigned short s; } cv; cv.b = hbf;
        hb[r] = cv.s;
        int m  = quad * 4 + r;
        int sg = (col >> 3) ^ (m & 7);
        dst[m * 64 + sg * 8 + (col & 7)] = hbf;
      }
    }

    __syncthreads();

    if (role == 0) {
      if (grp == 0) {
        xA0 = xB0;
        if (quad == 0) {
          bf16x8 f = bfzero();
          f[0] = (__bf16)xraw.x; f[1] = (__bf16)xraw.y;
          f[2] = (__bf16)xraw.z; f[3] = (__bf16)xraw.w;
          xB0 = f;
          if (t + 3 < TLEN)
            xraw = *(const float4*)(p.x + ((size_t)(b0 + l15) * TLEN + (t + 3)) * 4);
        }
      }
      if (grp == 1 && (unsigned)t < (unsigned)TLEN) {
        int am = __shfl(a_pend, 0);
        if (am > ackW) ackW = am;
        if (lane == 0) a_pend = __hip_atomic_load(ackp, __ATOMIC_RELAXED, AG);
        if (t >= CAP && ackW < t - CAP + 1) {
          int v = ackW, it = 0;
          do {
            if (lane == 0) v = __hip_atomic_load(ackp, __ATOMIC_ACQUIRE, AG);
            v = __shfl(v, 0);
            if (v >= t - CAP + 1) break;
            __builtin_amdgcn_s_sleep(1);
          } while (++it < SPIN_CAP);
          ackW = v;
        }
        const int col = w * 16 + l15;
        unsigned* rdst = (unsigned*)(ringc + (size_t)(t & CM) * 1024);
#pragma unroll
        for (int r = 0; r < 4; r++) {
          unsigned v = hb[r];
          unsigned o = (unsigned)__shfl_xor((int)v, 1);
          if ((lane & 1) == 0) {
            int m = quad * 4 + r;
            __hip_atomic_store(&rdst[(m * 64 + col) >> 1], v | (o << 16), __ATOMIC_RELAXED, AG);
          }
        }
      }
      if (tid == 0 && s >= 2)
        __hip_atomic_store(flagp, s - 1, __ATOMIC_RELAXED, AG);
    } else {
      if (grp == 0) {
        int fm = __shfl(f_pend, 0);
        if (fm > W) W = fm;
        if (lane == 0) f_pend = __hip_atomic_load(flagp, __ATOMIC_RELAXED, AG);
        xA0 = xB0; xA1 = xB1; xB0 = xC0; xB1 = xC1;
        if (t + 3 < TLEN) {
          if (W < t + 4) {
            int v = W, it = 0;
            do {
              if (lane == 0) v = __hip_atomic_load(flagp, __ATOMIC_ACQUIRE, AG);
              v = __shfl(v, 0);
              if (v >= t + 4) break;
              __builtin_amdgcn_s_sleep(1);
            } while (++it < SPIN_CAP);
            W = v;
          }
          load_frag_pair(ringc + (size_t)((t + 3) & CM) * 1024, l15, quad, xC0, xC1);
        }
      }
      if (tid == 0)
        __hip_atomic_store(ackp, s + 2, __ATOMIC_RELAXED, AG);
    }
  }

  if (role == 1) {
    for (int i = tid; i < 2048; i += 512) s_fc1w[i] = p.fc1w[i];
    if (tid < 32) s_fc1b[tid] = p.fc1b[tid];
    if (tid < 96) s_fc2w[tid] = p.fc2w[tid];
    if (tid < 3)  s_fc2b[tid] = p.fc2b[tid];
    __syncthreads();
    {
      int m = tid >> 5, u = tid & 31;
      float sacc = s_fc1b[u];
      const float* wrow = &s_fc1w[u * 64];
      const __bf16* hfin = tiles[1][1];
#pragma unroll
      for (int k = 0; k < 64; k++) {
        int sg = (k >> 3) ^ (m & 7);
        sacc += (float)hfin[m * 64 + sg * 8 + (k & 7)] * wrow[k];
      }
      s_z[m * 32 + u] = fmaxf(sacc, 0.f);
    }
    __syncthreads();
    if (tid < 16) {
      int m = tid;
      float lg[3];
#pragma unroll
      for (int v = 0; v < 3; v++) {
        float sv = s_fc2b[v];
#pragma unroll
        for (int u = 0; u < 32; u++) sv += s_z[m * 32 + u] * s_fc2w[v * 32 + u];
        lg[v] = sv;
      }
      float mx = fmaxf(lg[0], fmaxf(lg[1], lg[2]));
      float e0 = __expf(lg[0] - mx), e1 = __expf(lg[1] - mx), e2 = __expf(lg[2] - mx);
      float inv = 1.f / (e0 + e1 + e2);
      float* o = p.out + (size_t)(b0 + m) * 3;
      o[0] = e0 * inv; o[1] = e1 * inv; o[2] = e2 * inv;
    }
  }
}

// =============== Kernel B: round-4 fallback (no ws use) ===============
__global__ __launch_bounds__(1024) void lstm_fused(Params p)
{
  const int chunk = blockIdx.x;
  const int b0   = chunk * 16;
  const int tid  = threadIdx.x;
  const int wave = tid >> 6;
  const int L    = wave >> 2;
  const int w    = wave & 3;
  const int lane = tid & 63;
  const int quad = lane >> 4;
  const int l15  = lane & 15;

  __shared__ __bf16 tiles[2][5][16 * 64];
  __shared__ float  s_fc1w[2048];
  __shared__ float  s_z[512];
  __shared__ float  s_fc1b[32];
  __shared__ float  s_fc2w[96];
  __shared__ float  s_fc2b[3];

  bf16x8 wf[4][4];
  float  bias[4];
  {
    const float* wih = p.wih[L];
    const float* whh = p.whh[L];
    const float* bih = p.bih[L];
    const float* bhh = p.bhh[L];
#pragma unroll
    for (int g = 0; g < 4; g++) {
      int n = g * 64 + w * 16 + l15;
      bias[g] = bih[n] + bhh[n];
      if (L == 0) {
        bf16x8 f = bfzero();
        if (quad == 0) {
#pragma unroll
          for (int j = 0; j < 4; j++) f[j] = (__bf16)wih[n * 4 + j];
        }
        wf[g][0] = f; wf[g][1] = bfzero();
      } else {
#pragma unroll
        for (int q = 0; q < 2; q++) {
          const float* s = wih + n * 64 + q * 32 + quad * 8;
          bf16x8 f;
#pragma unroll
          for (int j = 0; j < 8; j++) f[j] = (__bf16)s[j];
          wf[g][q] = f;
        }
      }
#pragma unroll
      for (int q = 0; q < 2; q++) {
        const float* s = whh + n * 64 + q * 32 + quad * 8;
        bf16x8 f;
#pragma unroll
        for (int j = 0; j < 8; j++) f[j] = (__bf16)s[j];
        wf[g][2 + q] = f;
      }
    }
  }

  { int* ti = (int*)tiles; for (int i = tid; i < 5120; i += 1024) ti[i] = 0; }
  float cst[4] = {0.f, 0.f, 0.f, 0.f};

  if (wave == 0 && quad == 0) {
    const float4 xv = *(const float4*)(p.x + ((size_t)(b0 + l15) * TLEN) * 4);
    __bf16 v[4] = {(__bf16)xv.x, (__bf16)xv.y, (__bf16)xv.z, (__bf16)xv.w};
    *(float2*)&tiles[0][0][l15 * 64 + (l15 & 7) * 8] = *(float2*)v;
  }
  __syncthreads();

  for (int s = 0; s < TLEN + 3; s++) {
    const int t  = s - L;
    const int pr = s & 1;
    const int pw = pr ^ 1;

    if ((unsigned)t < (unsigned)TLEN) {
      const __bf16* in  = tiles[pr][L];
      const __bf16* own = tiles[pr][L + 1];
      const int sg0 = quad ^ (l15 & 7);
      const int sg1 = (4 + quad) ^ (l15 & 7);
      bf16x8 xf0 = *(const bf16x8*)&in [l15 * 64 + sg0 * 8];
      bf16x8 xf1 = *(const bf16x8*)&in [l15 * 64 + sg1 * 8];
      bf16x8 hf0 = *(const bf16x8*)&own[l15 * 64 + sg0 * 8];
      bf16x8 hf1 = *(const bf16x8*)&own[l15 * 64 + sg1 * 8];

      f32x4 acc[4];
#pragma unroll
      for (int g = 0; g < 4; g++) { f32x4 a = {bias[g], bias[g], bias[g], bias[g]}; acc[g] = a; }
#pragma unroll
      for (int g = 0; g < 4; g++) {
        acc[g] = __builtin_amdgcn_mfma_f32_16x16x32_bf16(xf0, wf[g][0], acc[g], 0, 0, 0);
        acc[g] = __builtin_amdgcn_mfma_f32_16x16x32_bf16(xf1, wf[g][1], acc[g], 0, 0, 0);
        acc[g] = __builtin_amdgcn_mfma_f32_16x16x32_bf16(hf0, wf[g][2], acc[g], 0, 0, 0);
        acc[g] = __builtin_amdgcn_mfma_f32_16x16x32_bf16(hf1, wf[g][3], acc[g], 0, 0, 0);
      }

      if (wave == 0 && quad == 0 && t + 1 < TLEN) {
        const float4 xv = *(const float4*)(p.x + ((size_t)(b0 + l15) * TLEN + (t + 1)) * 4);
        __bf16 v[4] = {(__bf16)xv.x, (__bf16)xv.y, (__bf16)xv.z, (__bf16)xv.w};
        *(float2*)&tiles[pw][0][l15 * 64 + (l15 & 7) * 8] = *(float2*)v;
      }

      const int col = w * 16 + l15;
      __bf16* dst = tiles[pw][L + 1];
#pragma unroll
      for (int r = 0; r < 4; r++) {
        float ig = fast_sigmoid(acc[0][r]);
        float fg = fast_sigmoid(acc[1][r]);
        float gg = fast_tanh(acc[2][r]);
        float og = fast_sigmoid(acc[3][r]);
        float c = fg * cst[r] + ig * gg;
        cst[r] = c;
        float h = og * fast_tanh(c);
        int m  = quad * 4 + r;
        int sg = (col >> 3) ^ (m & 7);
        dst[m * 64 + sg * 8 + (col & 7)] = (__bf16)h;
      }
    }
    __syncthreads();
  }

  for (int i = tid; i < 2048; i += 1024) s_fc1w[i] = p.fc1w[i];
  if (tid < 32) s_fc1b[tid] = p.fc1b[tid];
  if (tid < 96) s_fc2w[tid] = p.fc2w[tid];
  if (tid < 3)  s_fc2b[tid] = p.fc2b[tid];
  __syncthreads();
  if (tid < 512) {
    int m = tid >> 5, u = tid & 31;
    float sacc = s_fc1b[u];
    const float* wrow = &s_fc1w[u * 64];
    const __bf16* hfin = tiles[1][4];
#pragma unroll
    for (int k = 0; k < 64; k++) {
      int sg = (k >> 3) ^ (m & 7);
      sacc += (float)hfin[m * 64 + sg * 8 + (k & 7)] * wrow[k];
    }
    s_z[m * 32 + u] = fmaxf(sacc, 0.f);
  }
  __syncthreads();
  if (tid < 16) {
    int m = tid;
    float lg[3];
#pragma unroll
    for (int v = 0; v < 3; v++) {
      float sv = s_fc2b[v];
#pragma unroll
      for (int u = 0; u < 32; u++) sv += s_z[m * 32 + u] * s_fc2w[v * 32 + u];
      lg[v] = sv;
    }
    float mx = fmaxf(lg[0], fmaxf(lg[1], lg[2]));
    float e0 = __expf(lg[0] - mx), e1 = __expf(lg[1] - mx), e2 = __expf(lg[2] - mx);
    float inv = 1.f / (e0 + e1 + e2);
    float* o = p.out + (size_t)(b0 + m) * 3;
    o[0] = e0 * inv; o[1] = e1 * inv; o[2] = e2 * inv;
  }
}

extern "C" void kernel_launch(void* const* d_in, const int* in_sizes, int n_in,
                              void* d_out, int out_size, void* d_ws, size_t ws_size,
                              hipStream_t stream)
{
  (void)in_sizes; (void)n_in; (void)out_size;
  Params p;
  p.x = (const float*)d_in[0];
  for (int l = 0; l < 4; l++) {
    p.wih[l] = (const float*)d_in[1 + 4 * l];
    p.whh[l] = (const float*)d_in[2 + 4 * l];
    p.bih[l] = (const float*)d_in[3 + 4 * l];
    p.bhh[l] = (const float*)d_in[4 + 4 * l];
  }
  p.fc1w = (const float*)d_in[17];
  p.fc1b = (const float*)d_in[18];
  p.fc2w = (const float*)d_in[19];
  p.fc2b = (const float*)d_in[20];
  p.out = (float*)d_out;
  p.ws  = (char*)d_ws;

  // no-wrap ring: 32KB flags + 64 chunks x 512 slots x 2KB = 32KB + 64MB
  const size_t need_nowrap = 32768ull + 512ull * (NCH * 2048ull);
  const size_t avail = (ws_size > 32768) ? (ws_size - 32768) : 0;
  int CAP = 1;
  while (CAP < 64 && (size_t)(CAP * 2) * (NCH * 2048ull) <= avail) CAP <<= 1;

  if (ws_size >= need_nowrap) {
    p.CAP = 512; p.CM = 511;
    hipLaunchKernelGGL(lstm_nowrap2, dim3(128), dim3(512), 0, stream, p);
  } else if (CAP >= 16) {
    p.CAP = CAP; p.CM = CAP - 1;
    hipLaunchKernelGGL(lstm_split, dim3(128), dim3(512), 0, stream, p);
  } else {
    p.CAP = 0; p.CM = 0;
    hipLaunchKernelGGL(lstm_fused, dim3(NCH), dim3(1024), 0, stream, p);
  }
}

// Round 8
// 766.403 us; speedup vs baseline: 1.0605x; 1.0605x over previous
//
#include <hip/hip_runtime.h>

// 4-layer LSTM (B=1024,T=512,H=64,G=256) + FC head.
// ROUND 15 (r8 of session): REMOVE THE INTRA-BLOCK LOCKSTEP.
//   r7: counted-waitcnt barrier = null (743 vs 745) -> vmcnt(0)-drain theory dead.
//   Model: superstep 3480cyc = 1500 issue/SIMD + ~2000 stall where BOTH resident waves
//   (same block, barrier-locked) sit in the same dependency-chain phase. Dataflow only
//   needs one-directional grp0->grp1 handoff + buffer-reuse safety, not lockstep.
// Kernel S (lstm_async): nowrap2 structure, s_barrier replaced by LDS progress flags +
//   4-deep tile ring (slot = s&3). Gates: own-grp min>=s-1; grp1 also grp0 min>=s-1;
//   grp0 also grp1 min>=s-3 (depth-4 overwrite safety). Waves skew up to 3 supersteps ->
//   stalls decorrelate on each SIMD. Cross-block flag without barrier: each producer-grp1
//   wave vmcnt(4) after its 4 ring stores (retires slots<=s-2); within-grp skew<=1 ->
//   wave0's flag=s-3 is durable; tail vmcnt(0)+flag=BIG. Consumer gate W>=t+3.
//   All spins tight + SPIN_CAP (wrong-not-hung on protocol bug).
// Kernel A (lstm_split): servo champion fallback (ws < 64MB). Kernel B: no-ws fallback.

#define TLEN 512
#define NCH  64
#define AG   __HIP_MEMORY_SCOPE_AGENT
#define WG   __HIP_MEMORY_SCOPE_WORKGROUP
#define SPIN_CAP 2000000
#define LOG2E 1.44269504f
#define TWOLOG2E 2.88539008f

typedef __bf16 bf16x8 __attribute__((ext_vector_type(8)));
typedef float  f32x4  __attribute__((ext_vector_type(4)));

struct Params {
  const float* x;
  const float* wih[4]; const float* whh[4];
  const float* bih[4]; const float* bhh[4];
  const float* fc1w; const float* fc1b;
  const float* fc2w; const float* fc2b;
  float* out; char* ws;
  int CAP; int CM;
};

__device__ __forceinline__ bf16x8 bfzero() {
  union { unsigned long long u[2]; bf16x8 v; } z; z.u[0] = 0ull; z.u[1] = 0ull; return z.v;
}
__device__ __forceinline__ float fast_sigmoid(float x) {
  return __builtin_amdgcn_rcpf(1.f + __expf(-x));
}
__device__ __forceinline__ float fast_tanh(float x) {
  float e = __expf(2.f * x);
  return 1.f - 2.f * __builtin_amdgcn_rcpf(e + 1.f);
}
__device__ __forceinline__ void load_frag_pair(const unsigned short* sb, int l15, int quad,
                                               bf16x8& f0, bf16x8& f1) {
  const unsigned long long* a = (const unsigned long long*)(sb + l15 * 64 + quad * 8);
  const unsigned long long* b = (const unsigned long long*)(sb + l15 * 64 + 32 + quad * 8);
  union { bf16x8 v; unsigned long long u[2]; } c0, c1;
  c0.u[0] = __hip_atomic_load(&a[0], __ATOMIC_RELAXED, AG);
  c0.u[1] = __hip_atomic_load(&a[1], __ATOMIC_RELAXED, AG);
  c1.u[0] = __hip_atomic_load(&b[0], __ATOMIC_RELAXED, AG);
  c1.u[1] = __hip_atomic_load(&b[1], __ATOMIC_RELAXED, AG);
  f0 = c0.v; f1 = c1.v;
}

// ============ Kernel S: barrier-free async pipeline (LDS progress flags) ============
__global__ __launch_bounds__(512, 2) void lstm_async(Params p)
{
  const int bid   = blockIdx.x;
  const int role  = bid >> 6;
  const int chunk = bid & 63;
  const int b0    = chunk * 16;
  const int tid   = threadIdx.x;
  const int wave  = tid >> 6;
  const int grp   = wave >> 2;
  const int w     = wave & 3;
  const int lane  = tid & 63;
  const int quad  = lane >> 4;
  const int l15   = lane & 15;
  const int L     = role * 2 + grp;

  __shared__ __bf16 tiles[4][2][1024];   // [slot s&3][grp][16x64 XOR-swizzled]
  __shared__ int    s_prog[2][4];        // per-grp per-wave completed superstep
  __shared__ float  s_fc1w[2048];
  __shared__ float  s_z[512];
  __shared__ float  s_fc1b[32];
  __shared__ float  s_fc2w[96];
  __shared__ float  s_fc2b[3];

  int* flagp = (int*)p.ws + chunk * 16;
  unsigned short* ringc = (unsigned short*)(p.ws + 32 * 1024) + (size_t)chunk * 512 * 1024;

  // ---- weight fragments wf[gate][frag]: 0-1 = Wih(K0..63), 2-3 = Whh(K0..63) ----
  // exp2 folding (r8-verified): i,f,o scaled -log2e; g scaled +2log2e.
  bf16x8 wf[4][4];
  float  bias[4];
  {
    const float gsc[4] = { -LOG2E, -LOG2E, TWOLOG2E, -LOG2E };
    const float* wih = p.wih[L];
    const float* whh = p.whh[L];
    const float* bih = p.bih[L];
    const float* bhh = p.bhh[L];
#pragma unroll
    for (int g = 0; g < 4; g++) {
      const float sc = gsc[g];
      int n = g * 64 + w * 16 + l15;
      bias[g] = (bih[n] + bhh[n]) * sc;
      if (L == 0) {                    // w_ih_0 is (256,4): K-pad, frag1 unused
        bf16x8 f = bfzero();
        if (quad == 0) {
#pragma unroll
          for (int j = 0; j < 4; j++) f[j] = (__bf16)(wih[n * 4 + j] * sc);
        }
        wf[g][0] = f; wf[g][1] = bfzero();
      } else {
#pragma unroll
        for (int q = 0; q < 2; q++) {
          const float* s = wih + n * 64 + q * 32 + quad * 8;
          bf16x8 f;
#pragma unroll
          for (int j = 0; j < 8; j++) f[j] = (__bf16)(s[j] * sc);
          wf[g][q] = f;
        }
      }
#pragma unroll
      for (int q = 0; q < 2; q++) {
        const float* s = whh + n * 64 + q * 32 + quad * 8;
        bf16x8 f;
#pragma unroll
        for (int j = 0; j < 8; j++) f[j] = (__bf16)(s[j] * sc);
        wf[g][2 + q] = f;
      }
    }
  }

  { int* ti = (int*)tiles; for (int i = tid; i < 4096; i += 512) ti[i] = 0; }
  if (tid < 8) s_prog[tid >> 2][tid & 3] = -1;
  float cst[4] = {0.f, 0.f, 0.f, 0.f};

  int W = -1000000000, f_pend = -1000000000;
  bf16x8 xA0 = bfzero(), xA1 = bfzero();
  bf16x8 xB0 = bfzero(), xB1 = bfzero();
  bf16x8 xC0 = bfzero(), xC1 = bfzero();
  float4 xraw = {0.f, 0.f, 0.f, 0.f};

  if (role == 0) {
    if (grp == 0 && quad == 0) {
      const float* xb = p.x + (size_t)(b0 + l15) * TLEN * 4;
      const float4 x0 = *(const float4*)(xb);
      const float4 x1 = *(const float4*)(xb + 4);
      xraw = *(const float4*)(xb + 8);
      bf16x8 f = bfzero();
      f[0] = (__bf16)x0.x; f[1] = (__bf16)x0.y; f[2] = (__bf16)x0.z; f[3] = (__bf16)x0.w;
      xA0 = f;
      bf16x8 g = bfzero();
      g[0] = (__bf16)x1.x; g[1] = (__bf16)x1.y; g[2] = (__bf16)x1.z; g[3] = (__bf16)x1.w;
      xB0 = g;
    }
  } else if (grp == 0) {
    // start gate: flag >= 10 means ring slots <= 10 drained (new flag semantics)
    int v = -1000000000, it = 0;
    do {
      if (lane == 0) v = __hip_atomic_load(flagp, __ATOMIC_ACQUIRE, AG);
      v = __shfl(v, 0);
      if (v >= 10) break;
    } while (++it < SPIN_CAP);
    W = v;
    load_frag_pair(ringc,        l15, quad, xA0, xA1);   // slot 0
    load_frag_pair(ringc + 1024, l15, quad, xB0, xB1);   // slot 1
    load_frag_pair(ringc + 2048, l15, quad, xC0, xC1);   // slot 2
  }
  __syncthreads();   // one-time: tiles zeroed + prog init visible

  const int SMAX = (role == 0) ? (TLEN + 2) : (TLEN + 1);
  for (int s = 0; s < SMAX; s++) {
    const int t  = s - grp;
    const int rd = (s - 1) & 3, wr = s & 3;
    unsigned hb[4];

    // ---- LDS progress gate (replaces s_barrier) ----
    {
      const int need_own = s - 1;
      const int need_oth = (grp == 0) ? (s - 3) : (s - 1);
      const int og = grp ^ 1;
      int it = 0;
      for (;;) {
        int o0 = __hip_atomic_load(&s_prog[grp][0], __ATOMIC_RELAXED, WG);
        int o1 = __hip_atomic_load(&s_prog[grp][1], __ATOMIC_RELAXED, WG);
        int o2 = __hip_atomic_load(&s_prog[grp][2], __ATOMIC_RELAXED, WG);
        int o3 = __hip_atomic_load(&s_prog[grp][3], __ATOMIC_RELAXED, WG);
        int e0 = __hip_atomic_load(&s_prog[og][0], __ATOMIC_RELAXED, WG);
        int e1 = __hip_atomic_load(&s_prog[og][1], __ATOMIC_RELAXED, WG);
        int e2 = __hip_atomic_load(&s_prog[og][2], __ATOMIC_RELAXED, WG);
        int e3 = __hip_atomic_load(&s_prog[og][3], __ATOMIC_RELAXED, WG);
        int mo = min(min(o0, o1), min(o2, o3));
        int me = min(min(e0, e1), min(e2, e3));
        if (mo >= need_own && me >= need_oth) break;
        if (++it >= SPIN_CAP) break;
      }
    }
    asm volatile("" ::: "memory");   // no hoisting of tile reads above the gate

    if ((unsigned)t < (unsigned)TLEN) {
      bf16x8 if0, if1;
      if (grp == 0) { if0 = xA0; if1 = xA1; }
      else {
        const __bf16* src = tiles[rd][0];
        int sg0 = quad ^ (l15 & 7);
        int sg1 = (4 + quad) ^ (l15 & 7);
        if0 = *(const bf16x8*)&src[l15 * 64 + sg0 * 8];
        if1 = *(const bf16x8*)&src[l15 * 64 + sg1 * 8];
      }
      bf16x8 hf0, hf1;
      {
        const __bf16* src = tiles[rd][grp];
        int sg0 = quad ^ (l15 & 7);
        int sg1 = (4 + quad) ^ (l15 & 7);
        hf0 = *(const bf16x8*)&src[l15 * 64 + sg0 * 8];
        hf1 = *(const bf16x8*)&src[l15 * 64 + sg1 * 8];
      }

      f32x4 acc[4];
#pragma unroll
      for (int g = 0; g < 4; g++) { f32x4 a = {bias[g], bias[g], bias[g], bias[g]}; acc[g] = a; }
      if (L == 0) {
#pragma unroll
        for (int g = 0; g < 4; g++)
          acc[g] = __builtin_amdgcn_mfma_f32_16x16x32_bf16(if0, wf[g][0], acc[g], 0, 0, 0);
      } else {
#pragma unroll
        for (int g = 0; g < 4; g++) {
          acc[g] = __builtin_amdgcn_mfma_f32_16x16x32_bf16(if0, wf[g][0], acc[g], 0, 0, 0);
          acc[g] = __builtin_amdgcn_mfma_f32_16x16x32_bf16(if1, wf[g][1], acc[g], 0, 0, 0);
        }
      }
#pragma unroll
      for (int g = 0; g < 4; g++) {
        acc[g] = __builtin_amdgcn_mfma_f32_16x16x32_bf16(hf0, wf[g][2], acc[g], 0, 0, 0);
        acc[g] = __builtin_amdgcn_mfma_f32_16x16x32_bf16(hf1, wf[g][3], acc[g], 0, 0, 0);
      }

      // cell (exp2-folded): acc_i/f/o = -log2e*pre, acc_g = 2log2e*pre
      const int col = w * 16 + l15;
      __bf16* dst = tiles[wr][grp];
#pragma unroll
      for (int r = 0; r < 4; r++) {
        float ig = __builtin_amdgcn_rcpf(1.f + __builtin_amdgcn_exp2f(acc[0][r]));
        float fg = __builtin_amdgcn_rcpf(1.f + __builtin_amdgcn_exp2f(acc[1][r]));
        float gg = 1.f - 2.f * __builtin_amdgcn_rcpf(1.f + __builtin_amdgcn_exp2f(acc[2][r]));
        float og = __builtin_amdgcn_rcpf(1.f + __builtin_amdgcn_exp2f(acc[3][r]));
        float c  = fg * cst[r] + ig * gg;
        cst[r] = c;
        float th = 1.f - 2.f * __builtin_amdgcn_rcpf(1.f + __builtin_amdgcn_exp2f(TWOLOG2E * c));
        float h  = og * th;
        __bf16 hbf = (__bf16)h;
        union { __bf16 b; unsigned short s; } cv; cv.b = hbf;
        hb[r] = cv.s;
        int m  = quad * 4 + r;
        int sg = (col >> 3) ^ (m & 7);
        dst[m * 64 + sg * 8 + (col & 7)] = hbf;
      }
    }

    // ---- publish wave progress (tile writes drained first) ----
    asm volatile("s_waitcnt lgkmcnt(0)" ::: "memory");
    if (lane == 0) __hip_atomic_store(&s_prog[grp][w], s, __ATOMIC_RELAXED, WG);

    // -------- global work (no barrier; per-wave) --------
    if (role == 0) {
      if (grp == 0) {
        xA0 = xB0;
        if (quad == 0) {
          bf16x8 f = bfzero();
          f[0] = (__bf16)xraw.x; f[1] = (__bf16)xraw.y;
          f[2] = (__bf16)xraw.z; f[3] = (__bf16)xraw.w;
          xB0 = f;
          if (t + 3 < TLEN)
            xraw = *(const float4*)(p.x + ((size_t)(b0 + l15) * TLEN + (t + 3)) * 4);
        }
      } else {
        if ((unsigned)t < (unsigned)TLEN) {
          // slot t written exactly once, never overwritten
          const int col = w * 16 + l15;
          unsigned* rdst = (unsigned*)(ringc + (size_t)t * 1024);
#pragma unroll
          for (int r = 0; r < 4; r++) {
            unsigned v = hb[r];
            unsigned o = (unsigned)__shfl_xor((int)v, 1);
            if ((lane & 1) == 0) {
              int m = quad * 4 + r;
              __hip_atomic_store(&rdst[(m * 64 + col) >> 1], v | (o << 16), __ATOMIC_RELAXED, AG);
            }
          }
          asm volatile("s_waitcnt vmcnt(4)" ::: "memory");  // retires slots <= t-1
          // within-grp skew <=1 (own-grp gate) -> all grp1 waves retired slots <= s-3
          if (w == 0 && lane == 0 && s >= 3)
            __hip_atomic_store(flagp, s - 3, __ATOMIC_RELAXED, AG);
        } else {
          asm volatile("s_waitcnt vmcnt(0)" ::: "memory");  // tail: all drained
          if (w == 0 && lane == 0)
            __hip_atomic_store(flagp, 1000000, __ATOMIC_RELAXED, AG);
        }
      }
    } else {
      if (grp == 0) {
        int fm = __shfl(f_pend, 0);
        if (fm > W) W = fm;
        if (lane == 0) f_pend = __hip_atomic_load(flagp, __ATOMIC_RELAXED, AG);
        xA0 = xB0; xA1 = xB1; xB0 = xC0; xB1 = xC1;
        if (t + 3 < TLEN) {
          if (W < t + 3) {                 // flag f => slots <= f drained
            int v = W, it = 0;
            do {
              if (lane == 0) v = __hip_atomic_load(flagp, __ATOMIC_ACQUIRE, AG);
              v = __shfl(v, 0);
              if (v >= t + 3) break;
            } while (++it < SPIN_CAP);
            W = v;
          }
          load_frag_pair(ringc + (size_t)(t + 3) * 1024, l15, quad, xC0, xC1);
        }
      }
    }
  }

  // ---- FC head + softmax (consumer; grp1 final write at s=512 -> slot 0) ----
  if (role == 1) {
    __syncthreads();   // cold path: all waves done
    for (int i = tid; i < 2048; i += 512) s_fc1w[i] = p.fc1w[i];
    if (tid < 32) s_fc1b[tid] = p.fc1b[tid];
    if (tid < 96) s_fc2w[tid] = p.fc2w[tid];
    if (tid < 3)  s_fc2b[tid] = p.fc2b[tid];
    __syncthreads();
    {
      int m = tid >> 5, u = tid & 31;
      float sacc = s_fc1b[u];
      const float* wrow = &s_fc1w[u * 64];
      const __bf16* hfin = tiles[0][1];
#pragma unroll
      for (int k = 0; k < 64; k++) {
        int sg = (k >> 3) ^ (m & 7);
        sacc += (float)hfin[m * 64 + sg * 8 + (k & 7)] * wrow[k];
      }
      s_z[m * 32 + u] = fmaxf(sacc, 0.f);
    }
    __syncthreads();
    if (tid < 16) {
      int m = tid;
      float lg[3];
#pragma unroll
      for (int v = 0; v < 3; v++) {
        float sv = s_fc2b[v];
#pragma unroll
        for (int u = 0; u < 32; u++) sv += s_z[m * 32 + u] * s_fc2w[v * 32 + u];
        lg[v] = sv;
      }
      float mx = fmaxf(lg[0], fmaxf(lg[1], lg[2]));
      float e0 = __expf(lg[0] - mx), e1 = __expf(lg[1] - mx), e2 = __expf(lg[2] - mx);
      float inv = 1.f / (e0 + e1 + e2);
      float* o = p.out + (size_t)(b0 + m) * 3;
      o[0] = e0 * inv; o[1] = e1 * inv; o[2] = e2 * inv;
    }
  }
}

// ================= Kernel A: servo champion (794us) — fallback ws<64MB ==================
__global__ __launch_bounds__(512, 2) void lstm_split(Params p)
{
  const int bid   = blockIdx.x;
  const int role  = bid >> 6;
  const int chunk = bid & 63;
  const int b0    = chunk * 16;
  const int tid   = threadIdx.x;
  const int wave  = tid >> 6;
  const int grp   = wave >> 2;
  const int w     = wave & 3;
  const int lane  = tid & 63;
  const int quad  = lane >> 4;
  const int l15   = lane & 15;
  const int L     = role * 2 + grp;

  __shared__ __bf16 tiles[2][2][1024];
  __shared__ float  s_fc1w[2048];
  __shared__ float  s_z[512];
  __shared__ float  s_fc1b[32];
  __shared__ float  s_fc2w[96];
  __shared__ float  s_fc2b[3];

  int* flagp = (int*)p.ws + chunk * 16;
  int* ackp  = (int*)(p.ws + 16 * 1024) + chunk * 16;
  unsigned short* ringc = (unsigned short*)(p.ws + 32 * 1024) + (size_t)chunk * p.CAP * 1024;
  const int CAP = p.CAP, CM = p.CM;

  bf16x8 wf[4][4];
  float  bias[4];
  {
    const float gsc[4] = { -LOG2E, -LOG2E, TWOLOG2E, -LOG2E };
    const float* wih = p.wih[L];
    const float* whh = p.whh[L];
    const float* bih = p.bih[L];
    const float* bhh = p.bhh[L];
#pragma unroll
    for (int g = 0; g < 4; g++) {
      const float sc = gsc[g];
      int n = g * 64 + w * 16 + l15;
      bias[g] = (bih[n] + bhh[n]) * sc;
      if (L == 0) {
        bf16x8 f = bfzero();
        if (quad == 0) {
#pragma unroll
          for (int j = 0; j < 4; j++) f[j] = (__bf16)(wih[n * 4 + j] * sc);
        }
        wf[g][0] = f; wf[g][1] = bfzero();
      } else {
#pragma unroll
        for (int q = 0; q < 2; q++) {
          const float* s = wih + n * 64 + q * 32 + quad * 8;
          bf16x8 f;
#pragma unroll
          for (int j = 0; j < 8; j++) f[j] = (__bf16)(s[j] * sc);
          wf[g][q] = f;
        }
      }
#pragma unroll
      for (int q = 0; q < 2; q++) {
        const float* s = whh + n * 64 + q * 32 + quad * 8;
        bf16x8 f;
#pragma unroll
        for (int j = 0; j < 8; j++) f[j] = (__bf16)(s[j] * sc);
        wf[g][2 + q] = f;
      }
    }
  }

  { int* ti = (int*)tiles; for (int i = tid; i < 2048; i += 512) ti[i] = 0; }
  float cst[4] = {0.f, 0.f, 0.f, 0.f};

  int W = -1000000000, f_pend = -1000000000;
  int ackW = -1000000000, a_pend = -1000000000;
  bf16x8 xA0 = bfzero(), xA1 = bfzero();
  bf16x8 xB0 = bfzero(), xB1 = bfzero();
  bf16x8 xC0 = bfzero(), xC1 = bfzero();
  float4 xraw = {0.f, 0.f, 0.f, 0.f};

  if (role == 0) {
    if (grp == 0 && quad == 0) {
      const float* xb = p.x + (size_t)(b0 + l15) * TLEN * 4;
      const float4 x0 = *(const float4*)(xb);
      const float4 x1 = *(const float4*)(xb + 4);
      xraw = *(const float4*)(xb + 8);
      bf16x8 f = bfzero();
      f[0] = (__bf16)x0.x; f[1] = (__bf16)x0.y; f[2] = (__bf16)x0.z; f[3] = (__bf16)x0.w;
      xA0 = f;
      bf16x8 g = bfzero();
      g[0] = (__bf16)x1.x; g[1] = (__bf16)x1.y; g[2] = (__bf16)x1.z; g[3] = (__bf16)x1.w;
      xB0 = g;
    }
  } else if (grp == 0) {
    int v = -1000000000, it = 0;
    do {
      if (lane == 0) v = __hip_atomic_load(flagp, __ATOMIC_ACQUIRE, AG);
      v = __shfl(v, 0);
      if (v >= 10) break;
      __builtin_amdgcn_s_sleep(1);
    } while (++it < SPIN_CAP);
    W = v;
    load_frag_pair(ringc,        l15, quad, xA0, xA1);
    load_frag_pair(ringc + 1024, l15, quad, xB0, xB1);
    load_frag_pair(ringc + 2048, l15, quad, xC0, xC1);
  }
  __syncthreads();

  const int SMAX = (role == 0) ? (TLEN + 2) : (TLEN + 1);
  for (int s = 0; s < SMAX; s++) {
    const int t  = s - grp;
    const int pr = s & 1, pw = pr ^ 1;
    unsigned hb[4];

    if ((unsigned)t < (unsigned)TLEN) {
      bf16x8 if0, if1;
      if (grp == 0) { if0 = xA0; if1 = xA1; }
      else {
        const __bf16* src = tiles[pr][0];
        int sg0 = quad ^ (l15 & 7);
        int sg1 = (4 + quad) ^ (l15 & 7);
        if0 = *(const bf16x8*)&src[l15 * 64 + sg0 * 8];
        if1 = *(const bf16x8*)&src[l15 * 64 + sg1 * 8];
      }
      bf16x8 hf0, hf1;
      {
        const __bf16* src = tiles[pr][grp];
        int sg0 = quad ^ (l15 & 7);
        int sg1 = (4 + quad) ^ (l15 & 7);
        hf0 = *(const bf16x8*)&src[l15 * 64 + sg0 * 8];
        hf1 = *(const bf16x8*)&src[l15 * 64 + sg1 * 8];
      }

      f32x4 acc[4];
#pragma unroll
      for (int g = 0; g < 4; g++) { f32x4 a = {bias[g], bias[g], bias[g], bias[g]}; acc[g] = a; }
      if (L == 0) {
#pragma unroll
        for (int g = 0; g < 4; g++)
          acc[g] = __builtin_amdgcn_mfma_f32_16x16x32_bf16(if0, wf[g][0], acc[g], 0, 0, 0);
      } else {
#pragma unroll
        for (int g = 0; g < 4; g++) {
          acc[g] = __builtin_amdgcn_mfma_f32_16x16x32_bf16(if0, wf[g][0], acc[g], 0, 0, 0);
          acc[g] = __builtin_amdgcn_mfma_f32_16x16x32_bf16(if1, wf[g][1], acc[g], 0, 0, 0);
        }
      }
#pragma unroll
      for (int g = 0; g < 4; g++) {
        acc[g] = __builtin_amdgcn_mfma_f32_16x16x32_bf16(hf0, wf[g][2], acc[g], 0, 0, 0);
        acc[g] = __builtin_amdgcn_mfma_f32_16x16x32_bf16(hf1, wf[g][3], acc[g], 0, 0, 0);
      }

      const int col = w * 16 + l15;
      __bf16* dst = tiles[pw][grp];
#pragma unroll
      for (int r = 0; r < 4; r++) {
        float ig = __builtin_amdgcn_rcpf(1.f + __builtin_amdgcn_exp2f(acc[0][r]));
        float fg = __builtin_amdgcn_rcpf(1.f + __builtin_amdgcn_exp2f(acc[1][r]));
        float gg = 1.f - 2.f * __builtin_amdgcn_rcpf(1.f + __builtin_amdgcn_exp2f(acc[2][r]));
        float og = __builtin_amdgcn_rcpf(1.f + __builtin_amdgcn_exp2f(acc[3][r]));
        float c  = fg * cst[r] + ig * gg;
        cst[r] = c;
        float th = 1.f - 2.f * __builtin_amdgcn_rcpf(1.f + __builtin_amdgcn_exp2f(TWOLOG2E * c));
        float h  = og * th;
        __bf16 hbf = (__bf16)h;
        union { __bf16 b; unsigned short s; } cv; cv.b = hbf;
        hb[r] = cv.s;
        int m  = quad * 4 + r;
        int sg = (col >> 3) ^ (m & 7);
        dst[m * 64 + sg * 8 + (col & 7)] = hbf;
      }
    }

    __syncthreads();

    if (role == 0) {
      if (grp == 0) {
        xA0 = xB0;
        if (quad == 0) {
          bf16x8 f = bfzero();
          f[0] = (__bf16)xraw.x; f[1] = (__bf16)xraw.y;
          f[2] = (__bf16)xraw.z; f[3] = (__bf16)xraw.w;
          xB0 = f;
          if (t + 3 < TLEN)
            xraw = *(const float4*)(p.x + ((size_t)(b0 + l15) * TLEN + (t + 3)) * 4);
        }
      }
      if (grp == 1 && (unsigned)t < (unsigned)TLEN) {
        int am = __shfl(a_pend, 0);
        if (am > ackW) ackW = am;
        if (lane == 0) a_pend = __hip_atomic_load(ackp, __ATOMIC_RELAXED, AG);
        if (t >= CAP && ackW < t - CAP + 1) {
          int v = ackW, it = 0;
          do {
            if (lane == 0) v = __hip_atomic_load(ackp, __ATOMIC_ACQUIRE, AG);
            v = __shfl(v, 0);
            if (v >= t - CAP + 1) break;
            __builtin_amdgcn_s_sleep(1);
          } while (++it < SPIN_CAP);
          ackW = v;
        }
        const int col = w * 16 + l15;
        unsigned* rdst = (unsigned*)(ringc + (size_t)(t & CM) * 1024);
#pragma unroll
        for (int r = 0; r < 4; r++) {
          unsigned v = hb[r];
          unsigned o = (unsigned)__shfl_xor((int)v, 1);
          if ((lane & 1) == 0) {
            int m = quad * 4 + r;
            __hip_atomic_store(&rdst[(m * 64 + col) >> 1], v | (o << 16), __ATOMIC_RELAXED, AG);
          }
        }
      }
      if (tid == 0 && s >= 2)
        __hip_atomic_store(flagp, s - 1, __ATOMIC_RELAXED, AG);
    } else {
      if (grp == 0) {
        int fm = __shfl(f_pend, 0);
        if (fm > W) W = fm;
        if (lane == 0) f_pend = __hip_atomic_load(flagp, __ATOMIC_RELAXED, AG);
        xA0 = xB0; xA1 = xB1; xB0 = xC0; xB1 = xC1;
        if (t + 3 < TLEN) {
          if (W < t + 4) {
            int v = W, it = 0;
            do {
              if (lane == 0) v = __hip_atomic_load(flagp, __ATOMIC_ACQUIRE, AG);
              v = __shfl(v, 0);
              if (v >= t + 4) break;
              __builtin_amdgcn_s_sleep(1);
            } while (++it < SPIN_CAP);
            W = v;
          }
          load_frag_pair(ringc + (size_t)((t + 3) & CM) * 1024, l15, quad, xC0, xC1);
        }
      }
      if (tid == 0)
        __hip_atomic_store(ackp, s + 2, __ATOMIC_RELAXED, AG);
    }
  }

  if (role == 1) {
    for (int i = tid; i < 2048; i += 512) s_fc1w[i] = p.fc1w[i];
    if (tid < 32) s_fc1b[tid] = p.fc1b[tid];
    if (tid < 96) s_fc2w[tid] = p.fc2w[tid];
    if (tid < 3)  s_fc2b[tid] = p.fc2b[tid];
    __syncthreads();
    {
      int m = tid >> 5, u = tid & 31;
      float sacc = s_fc1b[u];
      const float* wrow = &s_fc1w[u * 64];
      const __bf16* hfin = tiles[1][1];
#pragma unroll
      for (int k = 0; k < 64; k++) {
        int sg = (k >> 3) ^ (m & 7);
        sacc += (float)hfin[m * 64 + sg * 8 + (k & 7)] * wrow[k];
      }
      s_z[m * 32 + u] = fmaxf(sacc, 0.f);
    }
    __syncthreads();
    if (tid < 16) {
      int m = tid;
      float lg[3];
#pragma unroll
      for (int v = 0; v < 3; v++) {
        float sv = s_fc2b[v];
#pragma unroll
        for (int u = 0; u < 32; u++) sv += s_z[m * 32 + u] * s_fc2w[v * 32 + u];
        lg[v] = sv;
      }
      float mx = fmaxf(lg[0], fmaxf(lg[1], lg[2]));
      float e0 = __expf(lg[0] - mx), e1 = __expf(lg[1] - mx), e2 = __expf(lg[2] - mx);
      float inv = 1.f / (e0 + e1 + e2);
      float* o = p.out + (size_t)(b0 + m) * 3;
      o[0] = e0 * inv; o[1] = e1 * inv; o[2] = e2 * inv;
    }
  }
}

// =============== Kernel B: round-4 fallback (no ws use) ===============
__global__ __launch_bounds__(1024) void lstm_fused(Params p)
{
  const int chunk = blockIdx.x;
  const int b0   = chunk * 16;
  const int tid  = threadIdx.x;
  const int wave = tid >> 6;
  const int L    = wave >> 2;
  const int w    = wave & 3;
  const int lane = tid & 63;
  const int quad = lane >> 4;
  const int l15  = lane & 15;

  __shared__ __bf16 tiles[2][5][16 * 64];
  __shared__ float  s_fc1w[2048];
  __shared__ float  s_z[512];
  __shared__ float  s_fc1b[32];
  __shared__ float  s_fc2w[96];
  __shared__ float  s_fc2b[3];

  bf16x8 wf[4][4];
  float  bias[4];
  {
    const float* wih = p.wih[L];
    const float* whh = p.whh[L];
    const float* bih = p.bih[L];
    const float* bhh = p.bhh[L];
#pragma unroll
    for (int g = 0; g < 4; g++) {
      int n = g * 64 + w * 16 + l15;
      bias[g] = bih[n] + bhh[n];
      if (L == 0) {
        bf16x8 f = bfzero();
        if (quad == 0) {
#pragma unroll
          for (int j = 0; j < 4; j++) f[j] = (__bf16)wih[n * 4 + j];
        }
        wf[g][0] = f; wf[g][1] = bfzero();
      } else {
#pragma unroll
        for (int q = 0; q < 2; q++) {
          const float* s = wih + n * 64 + q * 32 + quad * 8;
          bf16x8 f;
#pragma unroll
          for (int j = 0; j < 8; j++) f[j] = (__bf16)s[j];
          wf[g][q] = f;
        }
      }
#pragma unroll
      for (int q = 0; q < 2; q++) {
        const float* s = whh + n * 64 + q * 32 + quad * 8;
        bf16x8 f;
#pragma unroll
        for (int j = 0; j < 8; j++) f[j] = (__bf16)s[j];
        wf[g][2 + q] = f;
      }
    }
  }

  { int* ti = (int*)tiles; for (int i = tid; i < 5120; i += 1024) ti[i] = 0; }
  float cst[4] = {0.f, 0.f, 0.f, 0.f};

  if (wave == 0 && quad == 0) {
    const float4 xv = *(const float4*)(p.x + ((size_t)(b0 + l15) * TLEN) * 4);
    __bf16 v[4] = {(__bf16)xv.x, (__bf16)xv.y, (__bf16)xv.z, (__bf16)xv.w};
    *(float2*)&tiles[0][0][l15 * 64 + (l15 & 7) * 8] = *(float2*)v;
  }
  __syncthreads();

  for (int s = 0; s < TLEN + 3; s++) {
    const int t  = s - L;
    const int pr = s & 1;
    const int pw = pr ^ 1;

    if ((unsigned)t < (unsigned)TLEN) {
      const __bf16* in  = tiles[pr][L];
      const __bf16* own = tiles[pr][L + 1];
      const int sg0 = quad ^ (l15 & 7);
      const int sg1 = (4 + quad) ^ (l15 & 7);
      bf16x8 xf0 = *(const bf16x8*)&in [l15 * 64 + sg0 * 8];
      bf16x8 xf1 = *(const bf16x8*)&in [l15 * 64 + sg1 * 8];
      bf16x8 hf0 = *(const bf16x8*)&own[l15 * 64 + sg0 * 8];
      bf16x8 hf1 = *(const bf16x8*)&own[l15 * 64 + sg1 * 8];

      f32x4 acc[4];
#pragma unroll
      for (int g = 0; g < 4; g++) { f32x4 a = {bias[g], bias[g], bias[g], bias[g]}; acc[g] = a; }
#pragma unroll
      for (int g = 0; g < 4; g++) {
        acc[g] = __builtin_amdgcn_mfma_f32_16x16x32_bf16(xf0, wf[g][0], acc[g], 0, 0, 0);
        acc[g] = __builtin_amdgcn_mfma_f32_16x16x32_bf16(xf1, wf[g][1], acc[g], 0, 0, 0);
        acc[g] = __builtin_amdgcn_mfma_f32_16x16x32_bf16(hf0, wf[g][2], acc[g], 0, 0, 0);
        acc[g] = __builtin_amdgcn_mfma_f32_16x16x32_bf16(hf1, wf[g][3], acc[g], 0, 0, 0);
      }

      if (wave == 0 && quad == 0 && t + 1 < TLEN) {
        const float4 xv = *(const float4*)(p.x + ((size_t)(b0 + l15) * TLEN + (t + 1)) * 4);
        __bf16 v[4] = {(__bf16)xv.x, (__bf16)xv.y, (__bf16)xv.z, (__bf16)xv.w};
        *(float2*)&tiles[pw][0][l15 * 64 + (l15 & 7) * 8] = *(float2*)v;
      }

      const int col = w * 16 + l15;
      __bf16* dst = tiles[pw][L + 1];
#pragma unroll
      for (int r = 0; r < 4; r++) {
        float ig = fast_sigmoid(acc[0][r]);
        float fg = fast_sigmoid(acc[1][r]);
        float gg = fast_tanh(acc[2][r]);
        float og = fast_sigmoid(acc[3][r]);
        float c = fg * cst[r] + ig * gg;
        cst[r] = c;
        float h = og * fast_tanh(c);
        int m  = quad * 4 + r;
        int sg = (col >> 3) ^ (m & 7);
        dst[m * 64 + sg * 8 + (col & 7)] = (__bf16)h;
      }
    }
    __syncthreads();
  }

  for (int i = tid; i < 2048; i += 1024) s_fc1w[i] = p.fc1w[i];
  if (tid < 32) s_fc1b[tid] = p.fc1b[tid];
  if (tid < 96) s_fc2w[tid] = p.fc2w[tid];
  if (tid < 3)  s_fc2b[tid] = p.fc2b[tid];
  __syncthreads();
  if (tid < 512) {
    int m = tid >> 5, u = tid & 31;
    float sacc = s_fc1b[u];
    const float* wrow = &s_fc1w[u * 64];
    const __bf16* hfin = tiles[1][4];
#pragma unroll
    for (int k = 0; k < 64; k++) {
      int sg = (k >> 3) ^ (m & 7);
      sacc += (float)hfin[m * 64 + sg * 8 + (k & 7)] * wrow[k];
    }
    s_z[m * 32 + u] = fmaxf(sacc, 0.f);
  }
  __syncthreads();
  if (tid < 16) {
    int m = tid;
    float lg[3];
#pragma unroll
    for (int v = 0; v < 3; v++) {
      float sv = s_fc2b[v];
#pragma unroll
      for (int u = 0; u < 32; u++) sv += s_z[m * 32 + u] * s_fc2w[v * 32 + u];
      lg[v] = sv;
    }
    float mx = fmaxf(lg[0], fmaxf(lg[1], lg[2]));
    float e0 = __expf(lg[0] - mx), e1 = __expf(lg[1] - mx), e2 = __expf(lg[2] - mx);
    float inv = 1.f / (e0 + e1 + e2);
    float* o = p.out + (size_t)(b0 + m) * 3;
    o[0] = e0 * inv; o[1] = e1 * inv; o[2] = e2 * inv;
  }
}

extern "C" void kernel_launch(void* const* d_in, const int* in_sizes, int n_in,
                              void* d_out, int out_size, void* d_ws, size_t ws_size,
                              hipStream_t stream)
{
  (void)in_sizes; (void)n_in; (void)out_size;
  Params p;
  p.x = (const float*)d_in[0];
  for (int l = 0; l < 4; l++) {
    p.wih[l] = (const float*)d_in[1 + 4 * l];
    p.whh[l] = (const float*)d_in[2 + 4 * l];
    p.bih[l] = (const float*)d_in[3 + 4 * l];
    p.bhh[l] = (const float*)d_in[4 + 4 * l];
  }
  p.fc1w = (const float*)d_in[17];
  p.fc1b = (const float*)d_in[18];
  p.fc2w = (const float*)d_in[19];
  p.fc2b = (const float*)d_in[20];
  p.out = (float*)d_out;
  p.ws  = (char*)d_ws;

  // no-wrap ring: 32KB flags + 64 chunks x 512 slots x 2KB = 32KB + 64MB
  const size_t need_nowrap = 32768ull + 512ull * (NCH * 2048ull);
  const size_t avail = (ws_size > 32768) ? (ws_size - 32768) : 0;
  int CAP = 1;
  while (CAP < 64 && (size_t)(CAP * 2) * (NCH * 2048ull) <= avail) CAP <<= 1;

  if (ws_size >= need_nowrap) {
    p.CAP = 512; p.CM = 511;
    hipLaunchKernelGGL(lstm_async, dim3(128), dim3(512), 0, stream, p);
  } else if (CAP >= 16) {
    p.CAP = CAP; p.CM = CAP - 1;
    hipLaunchKernelGGL(lstm_split, dim3(128), dim3(512), 0, stream, p);
  } else {
    p.CAP = 0; p.CM = 0;
    hipLaunchKernelGGL(lstm_fused, dim3(NCH), dim3(1024), 0, stream, p);
  }
}